// Round 16
// baseline (271.386 us; speedup 1.0000x reference)
//
#include <hip/hip_runtime.h>

// 2-layer GRU (B=4096, S=512, IN=4, H=32) + FC(32->32) + FC(32->1), fp32 in/out.
// R16 = R8's PASSING structure (4 waves: M0/M1 all-32-unit lane-local mains,
// H0 fp32-VALU x-preacts, H1 u-side MFMA preacts) + ONE change: KS=4 phase
// batching (130 barriers vs 514). Lane-local mapping (R4/R8-verified): tile
// j=2G+s, A-row c -> W row 32G+8*(c>>2)+4s+(c&3); D-row 4q+r -> unit 8q+4s+r
// = lane's own next-step B-frag element; h never leaves registers.
// Lags: M0 @ p: steps 4p+t, publish H1S[p&1]. H1 @ p in [1,128]: read
// H1S[(p+1)&1] (h1 of phase p-1), write AX1[(p+1)&1]. M1 @ p in [2,129]:
// steps 4(p-2)+t, read AX1[p&1] (matching-step u-preacts). H0 @ p: AX0 for
// phase p+1 -> AX0[(p+1)&1]; x loaded global->reg one phase ahead.
// Numerics = R7/R8/R10: W hi+lo bf16 chained, state bf16-hi, x-side exact.

#define SEQ 512
#define KS 4
#define NPH 128   // SEQ/KS
#define LOG2E 1.44269504088896340736f

// lgkm-only barrier (R10-verified): LDS ordering without draining vmcnt
#define BSYNC() asm volatile("s_waitcnt lgkmcnt(0)\ns_barrier" ::: "memory")

typedef __attribute__((ext_vector_type(8))) short  short8;
typedef __attribute__((ext_vector_type(4))) float  f32x4;
typedef __attribute__((ext_vector_type(4))) unsigned uint4v;

static __device__ __forceinline__ unsigned short f2bf(float f) {
    unsigned u = __builtin_bit_cast(unsigned, f);
    return (unsigned short)((u + 0x7fffu + ((u >> 16) & 1u)) >> 16);
}
static __device__ __forceinline__ float bf2f(unsigned short b) {
    return __builtin_bit_cast(float, ((unsigned)b) << 16);
}
static __device__ __forceinline__ unsigned cvtpk(float a, float b) {
    unsigned r;
    asm("v_cvt_pk_bf16_f32 %0, %1, %2" : "=v"(r) : "v"(a), "v"(b));
    return r;
}
static __device__ __forceinline__ float sigm(float x) {
    return __builtin_amdgcn_rcpf(1.0f + __builtin_amdgcn_exp2f(-LOG2E * x));
}
static __device__ __forceinline__ float tanh_(float x) {
    return 1.0f - 2.0f * __builtin_amdgcn_rcpf(1.0f + __builtin_amdgcn_exp2f((2.0f * LOG2E) * x));
}

#define MFMA(A, B, C) __builtin_amdgcn_mfma_f32_16x16x32_bf16((A), (B), (C), 0, 0, 0)

// (Whi + Wlo) * B + Cin, chained accumulate (2 MFMAs, depth 2) — R7 numerics
static __device__ __forceinline__ f32x4 side2(short8 Wh, short8 Wl, short8 B,
                                              f32x4 Cin) {
    f32x4 a = MFMA(Wh, B, Cin);
    a = MFMA(Wl, B, a);
    return a;
}

static __device__ __forceinline__ void cvt8(const float* p, short8& h8, short8& l8) {
    f32x4 v0 = *(const f32x4*)p;
    f32x4 v1 = *(const f32x4*)(p + 4);
#pragma unroll
    for (int e = 0; e < 8; ++e) {
        float v = (e < 4) ? v0[e] : v1[e - 4];
        unsigned short hb = f2bf(v);
        h8[e] = (short)hb;
        l8[e] = (short)f2bf(v - bf2f(hb));
    }
}

__global__ __launch_bounds__(256, 1) void gru_fused(
    const float* __restrict__ x,
    const float* __restrict__ Wih0, const float* __restrict__ Whh0,
    const float* __restrict__ bih0, const float* __restrict__ bhh0,
    const float* __restrict__ Wih1, const float* __restrict__ Whh1,
    const float* __restrict__ bih1, const float* __restrict__ bhh1,
    const float* __restrict__ Wfc2, const float* __restrict__ bfc2,
    const float* __restrict__ Wfc,  const float* __restrict__ bfc,
    float* __restrict__ out)
{
    const int tid  = threadIdx.x;
    const int lane = tid & 63;
    const int wid  = tid >> 6;      // 0=M0, 1=M1, 2=H0, 3=H1
    const int c    = lane & 15;     // batch col
    const int q    = lane >> 4;     // 0..3
    const int b0   = blockIdx.x * 16;

    // LDS: AX0: 2 bufs x 4 steps x 6 tiles x 64 lanes x 16B = 49152 B
    //      AX1: same = 49152 B
    //      H1S: 2 bufs x 4 steps x 64 x 16B = 8192 B
    __shared__ __align__(16) char smem[106496];
    f32x4*  AX0 = (f32x4*)smem;              // buf*1536 + t*384 + j*64 + lane
    f32x4*  AX1 = (f32x4*)(smem + 49152);
    uint4v* H1S = (uint4v*)(smem + 98304);   // buf*256 + t*64 + lane

    // defensive zero-init of all LDS
    {
        f32x4 z = {0.0f, 0.0f, 0.0f, 0.0f};
        f32x4* sp = (f32x4*)smem;
        for (int i = tid; i < 6656; i += 256) sp[i] = z;
    }
    __syncthreads();

    short8 wh[6], wl[6];        // M0/M1: Whh hi/lo; H1: Wih1 hi/lo
    f32x4  cin[6];              // H1: folded u-side biases
    f32x4  bn0 = {0, 0, 0, 0}, bn1 = {0, 0, 0, 0};  // mains: bhh n-slices
    f32x4  wx[24];              // H0: Wih0 rows fp32 (lane-local g)
    float  bxs[24];             // H0: folded biases
    f32x4  xn[4];               // H0: next-phase x (4 steps, batch c)

    if (wid == 0) {
#pragma unroll
        for (int j = 0; j < 6; ++j) {
            const int G = j >> 1, s = j & 1;
            const int rowA = 32 * G + 8 * (c >> 2) + 4 * s + (c & 3);
            cvt8(Whh0 + rowA * 32 + 8 * q, wh[j], wl[j]);
        }
        bn0 = *(const f32x4*)(bhh0 + 64 + 8 * q);
        bn1 = *(const f32x4*)(bhh0 + 64 + 8 * q + 4);
    } else if (wid == 1) {
#pragma unroll
        for (int j = 0; j < 6; ++j) {
            const int G = j >> 1, s = j & 1;
            const int rowA = 32 * G + 8 * (c >> 2) + 4 * s + (c & 3);
            cvt8(Whh1 + rowA * 32 + 8 * q, wh[j], wl[j]);
        }
        bn0 = *(const f32x4*)(bhh1 + 64 + 8 * q);
        bn1 = *(const f32x4*)(bhh1 + 64 + 8 * q + 4);
    } else if (wid == 2) {
        // H0: lane (c,q) computes preacts for units 8q+4s+r, batch c (fp32)
#pragma unroll
        for (int j = 0; j < 6; ++j)
#pragma unroll
            for (int r = 0; r < 4; ++r) {
                const int G = j >> 1, s = j & 1;
                const int g = 32 * G + 8 * q + 4 * s + r;
                wx[4 * j + r]  = *(const f32x4*)(Wih0 + g * 4);
                bxs[4 * j + r] = bih0[g] + ((G < 2) ? bhh0[g] : 0.0f);
            }
        // prologue: AX0 buf0 = phase 0 (steps 0..3); prefetch phase 1 x
#pragma unroll
        for (int t = 0; t < KS; ++t) {
            f32x4 xv = *(const f32x4*)(x + ((long)(b0 + c) * SEQ + t) * 4);
#pragma unroll
            for (int j = 0; j < 6; ++j) {
                f32x4 a;
#pragma unroll
                for (int r = 0; r < 4; ++r) {
                    f32x4 w = wx[4 * j + r];
                    a[r] = bxs[4 * j + r] + w[0] * xv[0] + w[1] * xv[1]
                         + w[2] * xv[2] + w[3] * xv[3];
                }
                AX0[t * 384 + j * 64 + lane] = a;
            }
        }
#pragma unroll
        for (int t = 0; t < KS; ++t)
            xn[t] = *(const f32x4*)(x + ((long)(b0 + c) * SEQ + KS + t) * 4);
    } else {
        // H1: Wih1 A-frags (permuted rows) + folded biases
#pragma unroll
        for (int j = 0; j < 6; ++j) {
            const int G = j >> 1, s = j & 1;
            const int rowA = 32 * G + 8 * (c >> 2) + 4 * s + (c & 3);
            cvt8(Wih1 + rowA * 32 + 8 * q, wh[j], wl[j]);
            const int bb = 32 * G + 8 * q + 4 * s;
            f32x4 b = *(const f32x4*)(bih1 + bb);
            if (G < 2) b += *(const f32x4*)(bhh1 + bb);
            cin[j] = b;
        }
    }

    uint4v sfrag = {0, 0, 0, 0};             // mains: own state B-frag (bf16 hi)
    float  hst[2][4] = {{0, 0, 0, 0}, {0, 0, 0, 0}};  // fp32 master state

    __syncthreads();

    // --------------- phase loop: 130 iterations, one barrier each ---------------
#pragma unroll 1
    for (int p = 0; p <= NPH + 1; ++p) {
        if (wid == 0) {
            if (p < NPH) {
                const f32x4* axb  = AX0 + (p & 1) * 1536 + lane;
                uint4v*      hdst = H1S + (p & 1) * 256 + lane;
#pragma unroll
                for (int t = 0; t < KS; ++t) {
                    f32x4 a0 = axb[t * 384 + 0];
                    f32x4 a1 = axb[t * 384 + 64];
                    f32x4 a2 = axb[t * 384 + 128];
                    f32x4 a3 = axb[t * 384 + 192];
                    f32x4 a4 = axb[t * 384 + 256];
                    f32x4 a5 = axb[t * 384 + 320];
                    const short8 B = __builtin_bit_cast(short8, sfrag);
                    f32x4 p0 = side2(wh[0], wl[0], B, a0);
                    f32x4 p1 = side2(wh[1], wl[1], B, a1);
                    f32x4 p2 = side2(wh[2], wl[2], B, a2);
                    f32x4 p3 = side2(wh[3], wl[3], B, a3);
                    f32x4 p4 = side2(wh[4], wl[4], B, bn0);
                    f32x4 p5 = side2(wh[5], wl[5], B, bn1);
                    float hv[2][4];
#pragma unroll
                    for (int s = 0; s < 2; ++s) {
                        const f32x4 pr  = s ? p1 : p0;
                        const f32x4 pz  = s ? p3 : p2;
                        const f32x4 pn  = s ? p5 : p4;
                        const f32x4 axn = s ? a5 : a4;
#pragma unroll
                        for (int r = 0; r < 4; ++r) {
                            float rg = sigm(pr[r]);
                            float zg = sigm(pz[r]);
                            float ng = tanh_(axn[r] + rg * pn[r]);
                            float hN = ng + zg * (hst[s][r] - ng);
                            hst[s][r] = hN;
                            hv[s][r] = hN;
                        }
                    }
                    unsigned w0 = cvtpk(hv[0][0], hv[0][1]);
                    unsigned w1 = cvtpk(hv[0][2], hv[0][3]);
                    unsigned w2 = cvtpk(hv[1][0], hv[1][1]);
                    unsigned w3 = cvtpk(hv[1][2], hv[1][3]);
                    uint4v ns = {w0, w1, w2, w3};
                    sfrag = ns;
                    hdst[t * 64] = sfrag;            // publish h1[4p+t]
                }
            }
        } else if (wid == 1) {
            if (p >= 2) {
                const f32x4* axb = AX1 + (p & 1) * 1536 + lane;
#pragma unroll
                for (int t = 0; t < KS; ++t) {
                    f32x4 a0 = axb[t * 384 + 0];
                    f32x4 a1 = axb[t * 384 + 64];
                    f32x4 a2 = axb[t * 384 + 128];
                    f32x4 a3 = axb[t * 384 + 192];
                    f32x4 a4 = axb[t * 384 + 256];
                    f32x4 a5 = axb[t * 384 + 320];
                    const short8 B = __builtin_bit_cast(short8, sfrag);
                    f32x4 p0 = side2(wh[0], wl[0], B, a0);
                    f32x4 p1 = side2(wh[1], wl[1], B, a1);
                    f32x4 p2 = side2(wh[2], wl[2], B, a2);
                    f32x4 p3 = side2(wh[3], wl[3], B, a3);
                    f32x4 p4 = side2(wh[4], wl[4], B, bn0);
                    f32x4 p5 = side2(wh[5], wl[5], B, bn1);
                    float hv[2][4];
#pragma unroll
                    for (int s = 0; s < 2; ++s) {
                        const f32x4 pr  = s ? p1 : p0;
                        const f32x4 pz  = s ? p3 : p2;
                        const f32x4 pn  = s ? p5 : p4;
                        const f32x4 axn = s ? a5 : a4;
#pragma unroll
                        for (int r = 0; r < 4; ++r) {
                            float rg = sigm(pr[r]);
                            float zg = sigm(pz[r]);
                            float ng = tanh_(axn[r] + rg * pn[r]);
                            float hN = ng + zg * (hst[s][r] - ng);
                            hst[s][r] = hN;
                            hv[s][r] = hN;
                        }
                    }
                    unsigned w0 = cvtpk(hv[0][0], hv[0][1]);
                    unsigned w1 = cvtpk(hv[0][2], hv[0][3]);
                    unsigned w2 = cvtpk(hv[1][0], hv[1][1]);
                    unsigned w3 = cvtpk(hv[1][2], hv[1][3]);
                    uint4v ns = {w0, w1, w2, w3};
                    sfrag = ns;
                }
            }
        } else if (wid == 2) {
            // H0: AX0 for phase p+1 (fp32 x-matvec); prefetch x for p+2
            if (p + 1 < NPH) {
                f32x4* dstax = AX0 + ((p + 1) & 1) * 1536 + lane;
#pragma unroll
                for (int t = 0; t < KS; ++t) {
                    f32x4 xv = xn[t];
#pragma unroll
                    for (int j = 0; j < 6; ++j) {
                        f32x4 a;
#pragma unroll
                        for (int r = 0; r < 4; ++r) {
                            f32x4 w = wx[4 * j + r];
                            a[r] = bxs[4 * j + r] + w[0] * xv[0] + w[1] * xv[1]
                                 + w[2] * xv[2] + w[3] * xv[3];
                        }
                        dstax[t * 384 + j * 64] = a;
                    }
                }
            }
            if (p + 2 < NPH) {
#pragma unroll
                for (int t = 0; t < KS; ++t)
                    xn[t] = *(const f32x4*)(x + ((long)(b0 + c) * SEQ +
                                                 (p + 2) * KS + t) * 4);
            }
        } else {
            // H1: AX1 for M1's phase p+1 = Wih1 * h1[phase p-1] + biases
            if (p >= 1 && p <= NPH) {
                const uint4v* hsrc = H1S + ((p + 1) & 1) * 256 + lane;
                f32x4* dstax = AX1 + ((p + 1) & 1) * 1536 + lane;
#pragma unroll
                for (int t = 0; t < KS; ++t) {
                    const short8 uf = __builtin_bit_cast(short8, hsrc[t * 64]);
#pragma unroll
                    for (int j = 0; j < 6; ++j)
                        dstax[t * 384 + j * 64] = side2(wh[j], wl[j], uf, cin[j]);
                }
            }
        }
        BSYNC();
    }

    // ---------------- epilogue: out[b] = Weff . h2[b] + cst (R8-verified) ----
    if (wid == 1) {
        float acc = 0.0f;
#pragma unroll
        for (int s = 0; s < 2; ++s)
#pragma unroll
            for (int r = 0; r < 4; ++r) {
                const int u = 8 * q + 4 * s + r;
                float we = 0.0f;
                for (int j = 0; j < 32; ++j)
                    we += Wfc[j] * Wfc2[j * 32 + u];
                acc += we * hst[s][r];
            }
        acc += __shfl_xor(acc, 16);
        acc += __shfl_xor(acc, 32);
        if (q == 0) {
            float cst = bfc[0];
            for (int j = 0; j < 32; ++j) cst += Wfc[j] * bfc2[j];
            out[b0 + c] = acc + cst;
        }
    }
}

extern "C" void kernel_launch(void* const* d_in, const int* in_sizes, int n_in,
                              void* d_out, int out_size, void* d_ws, size_t ws_size,
                              hipStream_t stream) {
    const float* x    = (const float*)d_in[0];
    const float* Wih0 = (const float*)d_in[1];
    const float* Whh0 = (const float*)d_in[2];
    const float* bih0 = (const float*)d_in[3];
    const float* bhh0 = (const float*)d_in[4];
    const float* Wih1 = (const float*)d_in[5];
    const float* Whh1 = (const float*)d_in[6];
    const float* bih1 = (const float*)d_in[7];
    const float* bhh1 = (const float*)d_in[8];
    const float* Wfc2 = (const float*)d_in[9];
    const float* bfc2 = (const float*)d_in[10];
    const float* Wfc  = (const float*)d_in[11];
    const float* bfc  = (const float*)d_in[12];

    const int nblocks = out_size / 16;  // 4096/16 = 256
    hipLaunchKernelGGL(gru_fused, dim3(nblocks), dim3(256), 0, stream,
                       x, Wih0, Whh0, bih0, bhh0, Wih1, Whh1, bih1, bhh1,
                       Wfc2, bfc2, Wfc, bfc, (float*)d_out);
}

// Round 17
// 211.363 us; speedup vs baseline: 1.2840x; 1.2840x over previous
//
#include <hip/hip_runtime.h>

// 2-layer GRU (B=4096, S=512, IN=4, H=32) + FC(32->32) + FC(32->1), fp32 in/out.
// FINAL (R10 restore, session-best 211us): 8 waves/block = (role: main/helper)
// x (layer) x (unit-half hf); main+helper paired per SIMD. Helpers produce
// feed-forward preacts one step ahead into LDS (AX); mains run the pure
// recurrence (6 MFMA Whh hi/lo x state-bf16, C-in = AX preacts) -> gates ->
// pack. Scheduling: lgkm-only barrier (global loads stay in flight across
// barriers) + T14 split x-staging (issue at phase 0, ds_write at phase 8).
// Rationale: per-wave trans-pipe occupancy is the binding resource; this
// structure spreads 24 trans/step on each of 4 SIMDs with helpers on
// complementary pipes. Tested-and-refuted alternatives: merged helpers (R9),
// 2 blocks/CU (R11), VALU-rcp (R12), gate interleave (R13), solo-main phase
// batching (R16). Numerics: W hi+lo bf16 chained, state bf16-hi, x exact
// fp32 -> absmax 4.88e-4 (threshold 2.5e-3).
// Lags (verified R7): M0 step i @ iter i; H1 makes AX1[step i-1] @ iter i;
// M1 step i-2 @ iter i; 514 iterations.

#define SEQ 512
#define LOG2E 1.44269504088896340736f

// lgkm-only barrier: orders LDS producer->consumer without draining vmcnt
#define BSYNC() asm volatile("s_waitcnt lgkmcnt(0)\ns_barrier" ::: "memory")

typedef __attribute__((ext_vector_type(8))) short  short8;
typedef __attribute__((ext_vector_type(4))) float  f32x4;
typedef __attribute__((ext_vector_type(2))) unsigned uint2v;

static __device__ __forceinline__ unsigned short f2bf(float f) {
    unsigned u = __builtin_bit_cast(unsigned, f);
    return (unsigned short)((u + 0x7fffu + ((u >> 16) & 1u)) >> 16);
}
static __device__ __forceinline__ float bf2f(unsigned short b) {
    return __builtin_bit_cast(float, ((unsigned)b) << 16);
}
static __device__ __forceinline__ unsigned cvtpk(float a, float b) {
    unsigned r;
    asm("v_cvt_pk_bf16_f32 %0, %1, %2" : "=v"(r) : "v"(a), "v"(b));
    return r;
}
static __device__ __forceinline__ float sigm(float x) {
    return __builtin_amdgcn_rcpf(1.0f + __builtin_amdgcn_exp2f(-LOG2E * x));
}
static __device__ __forceinline__ float tanh_(float x) {
    return 1.0f - 2.0f * __builtin_amdgcn_rcpf(1.0f + __builtin_amdgcn_exp2f((2.0f * LOG2E) * x));
}

#define MFMA(A, B, C) __builtin_amdgcn_mfma_f32_16x16x32_bf16((A), (B), (C), 0, 0, 0)

// (Whi + Wlo) * B + Cin, chained accumulate (2 MFMAs, depth 2)
static __device__ __forceinline__ f32x4 side2(short8 Wh, short8 Wl, short8 B,
                                              f32x4 Cin) {
    f32x4 a = MFMA(Wh, B, Cin);
    a = MFMA(Wl, B, a);
    return a;
}

static __device__ __forceinline__ void cvt8(const float* p, short8& h8, short8& l8) {
    f32x4 v0 = *(const f32x4*)p;
    f32x4 v1 = *(const f32x4*)(p + 4);
#pragma unroll
    for (int e = 0; e < 8; ++e) {
        float v = (e < 4) ? v0[e] : v1[e - 4];
        unsigned short hb = f2bf(v);
        h8[e] = (short)hb;
        l8[e] = (short)f2bf(v - bf2f(hb));
    }
}

__global__ __launch_bounds__(512, 1) void gru_fused(
    const float* __restrict__ x,
    const float* __restrict__ Wih0, const float* __restrict__ Whh0,
    const float* __restrict__ bih0, const float* __restrict__ bhh0,
    const float* __restrict__ Wih1, const float* __restrict__ Whh1,
    const float* __restrict__ bih1, const float* __restrict__ bhh1,
    const float* __restrict__ Wfc2, const float* __restrict__ bfc2,
    const float* __restrict__ Wfc,  const float* __restrict__ bfc,
    float* __restrict__ out)
{
    const int tid  = threadIdx.x;
    const int lane = tid & 63;
    const int wid  = tid >> 6;          // 0..7  (SIMD = wid & 3)
    const int role = wid >> 2;          // 0 = main, 1 = helper
    const int L    = (wid >> 1) & 1;    // layer
    const int hf   = wid & 1;           // unit half
    const int c    = lane & 15;         // batch col
    const int q    = lane >> 4;         // 0..3
    const int b0   = blockIdx.x * 16;

    // LDS map:
    //  ST01: h1 frags (L0 state AND L1-helper input), 2 bufs x [16][80B] = 2560
    //  ST2 : h2 frags, 2 bufs x [16][80B]                                = 2560
    //  XS  : x ring, 32 steps x 16 rows x 16B                            = 8192
    //  AX0 : L0 preact, 2 bufs x 6 tiles x 4 q x 16 c x f32x4            = 12288
    //  AX1 : L1 preact, same                                             = 12288
    //  EP  : epilogue scratch                                            = 128
    __shared__ __align__(16) char smem[38016];
    char*  ST01 = smem;
    char*  ST2  = smem + 2560;
    f32x4* XS   = (f32x4*)(smem + 5120);
    f32x4* AX0  = (f32x4*)(smem + 13312);
    f32x4* AX1  = (f32x4*)(smem + 25600);
    float* EP   = (float*)(smem + 37888);

    // zero state buffers (h = 0)
    for (int i = tid; i < 1280; i += 512) ((unsigned*)smem)[i] = 0u;

    // stage x steps 0..31
    if (tid < 256) {
        const int row = tid & 15, so = tid >> 4;
#pragma unroll
        for (int k = 0; k < 2; ++k) {
            const int step = so + 16 * k;
            XS[step * 16 + row] =
                *(const f32x4*)(x + ((long)(b0 + row) * SEQ + step) * 4);
        }
    }

    const int tts[3] = {hf, 2 + hf, 4 + hf};   // r,z,n tiles for this half

    // ------------- per-role weight setup (wave-uniform branches) -----------
    short8 whhh[3], whhl[3];            // mains: Whh hi/lo
    f32x4  bhv2 = {0, 0, 0, 0};        // mains: bhh n-slice (C-in for j=2)
    f32x4  wx0[12];                     // L0 helper: Wih0 rows fp32
    float  bxs[12];                     // L0 helper: folded biases
    short8 wuh[3], wul[3];              // L1 helper: Wih1 hi/lo
    f32x4  bxv[3];                      // L1 helper: folded biases

    if (role == 0) {
        const float* Whp = L ? Whh1 : Whh0;
        const float* bhp = L ? bhh1 : bhh0;
#pragma unroll
        for (int j = 0; j < 3; ++j)
            cvt8(Whp + (16 * tts[j] + c) * 32 + 8 * q, whhh[j], whhl[j]);
        bhv2 = *(const f32x4*)(bhp + 16 * tts[2] + 4 * q);
    } else if (L == 0) {
#pragma unroll
        for (int j = 0; j < 3; ++j)
#pragma unroll
            for (int r = 0; r < 4; ++r) {
                const int g = 16 * tts[j] + 4 * q + r;
                wx0[4 * j + r] = *(const f32x4*)(Wih0 + g * 4);
                bxs[4 * j + r] = bih0[g] + ((j < 2) ? bhh0[g] : 0.0f);
            }
    } else {
#pragma unroll
        for (int j = 0; j < 3; ++j) {
            cvt8(Wih1 + (16 * tts[j] + c) * 32 + 8 * q, wuh[j], wul[j]);
            f32x4 bb = *(const f32x4*)(bih1 + 16 * tts[j] + 4 * q);
            if (j < 2) bb += *(const f32x4*)(bhh1 + 16 * tts[j] + 4 * q);
            bxv[j] = bb;
        }
    }

    // prologue: L0 helper fills AX0 buf0 with step 0 (direct global x read)
    if (role == 1 && L == 0) {
        f32x4 xv = *(const f32x4*)(x + (long)(b0 + c) * (SEQ * 4));
#pragma unroll
        for (int j = 0; j < 3; ++j) {
            f32x4 a;
#pragma unroll
            for (int r = 0; r < 4; ++r) {
                f32x4 w = wx0[4 * j + r];
                a[r] = bxs[4 * j + r] + w[0] * xv[0] + w[1] * xv[1]
                     + w[2] * xv[2] + w[3] * xv[3];
            }
            AX0[tts[j] * 64 + q * 16 + c] = a;
        }
    }

    float hst[4] = {0, 0, 0, 0};   // mains: units 16hf+4q+r, batch c
    f32x4 xr0 = {0, 0, 0, 0}, xr1 = {0, 0, 0, 0};   // T14 staging regs (helpers)
    const int frag_off = c * 80 + q * 16;                 // b128 B-frag read
    const int wr_off   = c * 80 + (16 * hf + 4 * q) * 2;  // b64 D write (hi)

    __syncthreads();

    // ---------------- pipelined main loop: 514 iterations ----------------
    // iter i: L0 main: step i (i<SEQ); reads AX0[i&1], state ST01[(i+1)&1],
    //                  writes h1[i] -> ST01[i&1].
    //         L0 helper: AX0 for step i+1 -> AX0[(i+1)&1]; x staging (T14).
    //         L1 helper: P[i] = Wih1*h1[i-1] (ST01[(i+1)&1]) -> AX1[i&1].
    //         L1 main: step i-2 (i>=2); reads AX1[(i+1)&1], state ST2[(i+1)&1],
    //                  writes h2[i-2] -> ST2[i&1].
#pragma unroll 2
    for (int i = 0; i <= SEQ + 1; ++i) {
        if (role == 0) {
            const bool act = (L == 0) ? (i < SEQ) : (i >= 2);
            if (act) {
                const char*  st;
                const f32x4* axb;
                char*        dst;
                if (L == 0) {
                    st  = ST01 + ((i + 1) & 1) * 1280;
                    axb = AX0 + (i & 1) * 384;
                    dst = ST01 + (i & 1) * 1280;
                } else {
                    st  = ST2 + ((i + 1) & 1) * 1280;
                    axb = AX1 + ((i + 1) & 1) * 384;
                    dst = ST2 + (i & 1) * 1280;
                }
                short8 sfrag = *(const short8*)(st + frag_off);
                f32x4 ax0v = axb[tts[0] * 64 + q * 16 + c];
                f32x4 ax1v = axb[tts[1] * 64 + q * 16 + c];
                f32x4 ax2v = axb[tts[2] * 64 + q * 16 + c];

                f32x4 p0 = side2(whhh[0], whhl[0], sfrag, ax0v);
                f32x4 p1 = side2(whhh[1], whhl[1], sfrag, ax1v);
                f32x4 p2 = side2(whhh[2], whhl[2], sfrag, bhv2);

                float hv[4];
#pragma unroll
                for (int r = 0; r < 4; ++r) {
                    float rg = sigm(p0[r]);
                    float zg = sigm(p1[r]);
                    float ng = tanh_(ax2v[r] + rg * p2[r]);
                    float hN = ng + zg * (hst[r] - ng);
                    hst[r] = hN;
                    hv[r] = hN;
                }
                unsigned w0 = cvtpk(hv[0], hv[1]);
                unsigned w1 = cvtpk(hv[2], hv[3]);
                uint2v wpk = {w0, w1};
                *(uint2v*)(dst + wr_off) = wpk;
            }
        } else if (L == 0) {
            // ---- T14 x staging: issue loads at phase 0, ds_write at phase 8 ----
            if ((i & 15) == 0) {
                const int base = i + 16;
                if (base < SEQ) {
                    const int hidx = tid - 256;          // 0..127
                    const int row = hidx & 15, so = hidx >> 4;
                    xr0 = *(const f32x4*)(x + ((long)(b0 + row) * SEQ + base + so) * 4);
                    xr1 = *(const f32x4*)(x + ((long)(b0 + row) * SEQ + base + so + 8) * 4);
                }
            } else if ((i & 15) == 8) {
                const int base = i + 8;                  // == issue-time base
                if (base < SEQ) {
                    const int hidx = tid - 256;
                    const int row = hidx & 15, so = hidx >> 4;
                    XS[((base + so) & 31) * 16 + row] = xr0;
                    XS[((base + so + 8) & 31) * 16 + row] = xr1;
                }
            }
            // ---- AX0 for step i+1 (exact fp32 x-matvec) ----
            const int step = i + 1;
            if (step < SEQ) {
                f32x4 xv = XS[(step & 31) * 16 + c];
                f32x4* dstax = AX0 + (step & 1) * 384;
#pragma unroll
                for (int j = 0; j < 3; ++j) {
                    f32x4 a;
#pragma unroll
                    for (int r = 0; r < 4; ++r) {
                        f32x4 w = wx0[4 * j + r];
                        a[r] = bxs[4 * j + r] + w[0] * xv[0] + w[1] * xv[1]
                             + w[2] * xv[2] + w[3] * xv[3];
                    }
                    dstax[tts[j] * 64 + q * 16 + c] = a;
                }
            }
        } else {
            // ---- L1 helper: P[i] = Wih1 * h1[i-1] + biases -> AX1[i&1] ----
            if (i >= 1 && i <= SEQ) {
                const char* us = ST01 + ((i + 1) & 1) * 1280;   // h1[i-1]
                short8 uf = *(const short8*)(us + frag_off);
                f32x4* dstax = AX1 + (i & 1) * 384;
#pragma unroll
                for (int j = 0; j < 3; ++j) {
                    f32x4 a = side2(wuh[j], wul[j], uf, bxv[j]);
                    dstax[tts[j] * 64 + q * 16 + c] = a;
                }
            }
        }
        BSYNC();
    }

    // ---------------- epilogue: out = Weff . h2 + cst ----------------
    if (role == 0 && L == 1) {
        float we[4] = {0, 0, 0, 0};
        const float* w2p = Wfc2 + 16 * hf + 4 * q;
#pragma unroll 8
        for (int j = 0; j < 32; ++j) {
            float wf = Wfc[j];
            f32x4 w2 = *(const f32x4*)(w2p + j * 32);
#pragma unroll
            for (int r = 0; r < 4; ++r) we[r] += wf * w2[r];
        }
        float acc = we[0] * hst[0] + we[1] * hst[1] + we[2] * hst[2] + we[3] * hst[3];
        acc += __shfl_xor(acc, 16);
        acc += __shfl_xor(acc, 32);
        if (q == 0) EP[hf * 16 + c] = acc;
    }
    __syncthreads();
    if (wid == 0 && q == 0) {
        float cst = bfc[0];
        for (int j = 0; j < 32; ++j) cst += Wfc[j] * bfc2[j];
        out[b0 + c] = EP[c] + EP[16 + c] + cst;
    }
}

extern "C" void kernel_launch(void* const* d_in, const int* in_sizes, int n_in,
                              void* d_out, int out_size, void* d_ws, size_t ws_size,
                              hipStream_t stream) {
    const float* x    = (const float*)d_in[0];
    const float* Wih0 = (const float*)d_in[1];
    const float* Whh0 = (const float*)d_in[2];
    const float* bih0 = (const float*)d_in[3];
    const float* bhh0 = (const float*)d_in[4];
    const float* Wih1 = (const float*)d_in[5];
    const float* Whh1 = (const float*)d_in[6];
    const float* bih1 = (const float*)d_in[7];
    const float* bhh1 = (const float*)d_in[8];
    const float* Wfc2 = (const float*)d_in[9];
    const float* bfc2 = (const float*)d_in[10];
    const float* Wfc  = (const float*)d_in[11];
    const float* bfc  = (const float*)d_in[12];

    const int nblocks = out_size / 16;  // 4096/16 = 256 -> 1 block/CU
    hipLaunchKernelGGL(gru_fused, dim3(nblocks), dim3(512), 0, stream,
                       x, Wih0, Whh0, bih0, bhh0, Wih1, Whh1, bih1, bhh1,
                       Wfc2, bfc2, Wfc, bfc, (float*)d_out);
}